// Round 9
// baseline (886.623 us; speedup 1.0000x reference)
//
#include <hip/hip_runtime.h>
#include <hip/hip_bf16.h>
#include <math.h>

#define NDIM 512
#define NB   128
#define NMAT 129
#define EPSF 1e-7f
#define MS  ((size_t)262144)   // matrix stride (floats) = 512*512
#define PSTR ((size_t)524288)  // E2 plane stride (floats) = 512*512*2
#define LTS2 ((size_t)65536)   // Lt stride per matrix = 128 cols * 512 rows

// workspace layout (float offsets)
#define OFF_E   ((size_t)0)                    // 1,048,576
#define OFF_WM  ((size_t)1048576)              // 262,144
#define OFF_IPR ((size_t)1310720)              // 65,536
#define OFF_LPR ((size_t)1376256)              // 128
#define OFF_LD  ((size_t)1376384)              // 129
#define OFF_MAT ((size_t)1377792)              // 129*262144
#define OFF_LT  ((size_t)(OFF_MAT + (size_t)NMAT*MS))  // 129*65536 -> total ~167 MB

__device__ __forceinline__ float rdlane(float v, int l) {
  return __uint_as_float((unsigned)__builtin_amdgcn_readlane((int)__float_as_uint(v), l));
}

// ---------- fused Wm + E-IPF ----------
__global__ __launch_bounds__(256) void k_prep(const float* __restrict__ W, const float* __restrict__ Vc,
                                              const float* __restrict__ Ec, float* __restrict__ Wm,
                                              float* __restrict__ E2) {
  int idx = blockIdx.x * 256 + threadIdx.x;   // i*512 + j
  int i = idx >> 9, j = idx & 511;
  float wv = 0.f;
  if (i > j)      wv = 1.f / (1.f + expf(-W[i*NDIM + j]));
  else if (i < j) wv = 1.f / (1.f + expf(-W[j*NDIM + i]));
  Wm[idx] = wv;
  float vi0 = Vc[2*i], vi1 = Vc[2*i+1];
  float mi = fmaxf(vi0, vi1);
  float ei0 = expf(vi0 - mi), ei1 = expf(vi1 - mi);
  float si = ei0 + ei1;
  float A0 = ei0 / si, A1 = ei1 / si;
  float vj0 = Vc[2*j], vj1 = Vc[2*j+1];
  float mj = fmaxf(vj0, vj1);
  float ej0 = expf(vj0 - mj), ej1 = expf(vj1 - mj);
  float sj = ej0 + ej1;
  float B0 = ej0 / sj, B1 = ej1 / sj;
  float4 ec = reinterpret_cast<const float4*>(Ec)[idx];
  float e00 = expf(ec.x), e01 = expf(ec.y), e10 = expf(ec.z), e11 = expf(ec.w);
  float s = e00 + e01 + e10 + e11;
  float inv = 1.f / s;
  e00 *= inv; e01 *= inv; e10 *= inv; e11 *= inv;
  for (int t = 0; t < 10; ++t) {
    float rm0 = e00 + e01 + EPSF, rm1 = e10 + e11 + EPSF;
    float cm0 = e00 + e10 + EPSF, cm1 = e01 + e11 + EPSF;
    float f0 = A0 / rm0, f1 = A1 / rm1;
    e00 *= f0; e01 *= f0; e10 *= f1; e11 *= f1;
    float g0 = B0 / cm0, g1 = B1 / cm1;
    e00 *= g0; e10 *= g0; e01 *= g1; e11 *= g1;
    float ss = e00 + e01 + e10 + e11 + EPSF;
    float iv = 1.f / ss;
    e00 *= iv; e01 *= iv; e10 *= iv; e11 *= iv;
  }
  if (i == j) { e00 = 0.f; e01 = 0.f; e10 = 0.f; e11 = 0.f; }
  e00 = fminf(fmaxf(e00, 0.f), 1.f);
  e01 = fminf(fmaxf(e01, 0.f), 1.f);
  e10 = fminf(fmaxf(e10, 0.f), 1.f);
  e11 = fminf(fmaxf(e11, 0.f), 1.f);
  reinterpret_cast<float2*>(E2)[idx]        = make_float2(e00, e01);
  reinterpret_cast<float2*>(E2 + PSTR)[idx] = make_float2(e10, e11);
}

// ---------- Pr, invPr, sum(log Pr) ----------
__global__ __launch_bounds__(256) void k_Pr(const int* __restrict__ x, const float* __restrict__ Vc,
                                            float* __restrict__ invPr, float* __restrict__ logPr) {
  const int b = blockIdx.x;
  const int tid = threadIdx.x;
  float acc = 0.f;
  for (int ii = tid; ii < NDIM; ii += 256) {
    const int xv = x[b*NDIM + ii];
    float v0 = Vc[2*ii], v1 = Vc[2*ii+1];
    float mx = fmaxf(v0, v1);
    float e0 = expf(v0 - mx), e1 = expf(v1 - mx);
    float s = e0 + e1;
    const float p = xv ? (e1 / s) : (e0 / s);
    invPr[b*NDIM + ii] = 1.f / p;
    acc += logf(p);
  }
  for (int off = 32; off > 0; off >>= 1) acc += __shfl_down(acc, off, 64);
  __shared__ float sw[4];
  if ((tid & 63) == 0) sw[tid >> 6] = acc;
  __syncthreads();
  if (tid == 0) logPr[b] = sw[0] + sw[1] + sw[2] + sw[3];
}

// ---------- build embedded minors ----------
__global__ __launch_bounds__(512) void k_build(const int* __restrict__ x, const float* __restrict__ E2,
                                               const float* __restrict__ Wm, const float* __restrict__ invPr,
                                               float* __restrict__ Mall) {
  const int b = blockIdx.x;
  const int i = blockIdx.y*8 + (threadIdx.x >> 6);
  const int lane = threadIdx.x & 63;
  const int j0 = lane << 3;

  const float4 w0 = *(const float4*)(Wm + (size_t)i*NDIM + j0);
  const float4 w1 = *(const float4*)(Wm + (size_t)i*NDIM + j0 + 4);
  float wp[8];
  if (b < NB) {
    const int   xi   = x[b*NDIM + i];
    const float ipri = invPr[b*NDIM + i];
    const int4  xa = *(const int4*)(x + b*NDIM + j0);
    const int4  xb = *(const int4*)(x + b*NDIM + j0 + 4);
    const float4 pa = *(const float4*)(invPr + b*NDIM + j0);
    const float4 pb = *(const float4*)(invPr + b*NDIM + j0 + 4);
    const float* pl = E2 + (size_t)xi*PSTR + ((size_t)i*NDIM + j0)*2;
    const float4 ea = *(const float4*)(pl);
    const float4 eb = *(const float4*)(pl + 4);
    const float4 ec = *(const float4*)(pl + 8);
    const float4 ed = *(const float4*)(pl + 12);
    wp[0] = w0.x * (xa.x ? ea.y : ea.x) * pa.x;
    wp[1] = w0.y * (xa.y ? ea.w : ea.z) * pa.y;
    wp[2] = w0.z * (xa.z ? eb.y : eb.x) * pa.z;
    wp[3] = w0.w * (xa.w ? eb.w : eb.z) * pa.w;
    wp[4] = w1.x * (xb.x ? ec.y : ec.x) * pb.x;
    wp[5] = w1.y * (xb.y ? ec.w : ec.z) * pb.y;
    wp[6] = w1.z * (xb.z ? ed.y : ed.x) * pb.z;
    wp[7] = w1.w * (xb.w ? ed.w : ed.z) * pb.w;
    #pragma unroll
    for (int k = 0; k < 8; ++k) wp[k] *= ipri;
  } else {
    wp[0]=w0.x; wp[1]=w0.y; wp[2]=w0.z; wp[3]=w0.w;
    wp[4]=w1.x; wp[5]=w1.y; wp[6]=w1.z; wp[7]=w1.w;
  }
  float s = ((wp[0]+wp[1])+(wp[2]+wp[3])) + ((wp[4]+wp[5])+(wp[6]+wp[7]));
  #pragma unroll
  for (int off = 32; off > 0; off >>= 1) s += __shfl_xor(s, off, 64);

  float o[8];
  #pragma unroll
  for (int k = 0; k < 8; ++k) o[k] = -wp[k];
  if (i == 0) {
    #pragma unroll
    for (int k = 0; k < 8; ++k) o[k] = 0.f;
    if (lane == 0) o[0] = 1.f;
  } else {
    if (lane == 0) o[0] = 0.f;
    #pragma unroll
    for (int k = 0; k < 8; ++k)
      if (j0 + k == i) o[k] = s;
  }
  float* dst = Mall + (size_t)b*MS + (size_t)i*NDIM + j0;
  *(float4*)(dst)   = make_float4(o[0],o[1],o[2],o[3]);
  *(float4*)(dst+4) = make_float4(o[4],o[5],o[6],o[7]);
}

// ---------- single-wave 64x64 LU via readlane ----------
template<int KK>
struct WFact {
  static __device__ __forceinline__ void run(float (&a)[64], const int lane,
                                             float& mypiv, float& myrec) {
    const float piv = rdlane(a[KK], KK);
    const float rec = 1.0f / piv;
    if (lane == KK) { mypiv = piv; myrec = rec; }
    if (lane > KK) {
      const float l = a[KK] * rec;
      a[KK] = l;
      #pragma unroll
      for (int c = KK + 1; c < 64; ++c)
        a[c] -= l * rdlane(a[c], KK);
    }
    WFact<KK + 1>::run(a, lane, mypiv, myrec);
  }
};
template<>
struct WFact<64> {
  static __device__ __forceinline__ void run(float (&)[64], int, float&, float&) {}
};

// ---------- L21 row triangular solve ----------
template<int C>
struct SolveStep {
  static __device__ __forceinline__ void run(float (&a)[64], const float (*T)[68]) {
    float acc = a[C];
    #pragma unroll
    for (int p = 0; p < C; ++p)
      acc -= a[p] * T[C][p];
    a[C] = acc * T[C][66];
    SolveStep<C + 1>::run(a, T);
  }
};
template<>
struct SolveStep<64> {
  static __device__ __forceinline__ void run(float (&)[64], const float (*)[68]) {}
};

// ---------- panel A, 8-way split: every block redo's diag0 LU (identical T),
// wave1 solves a slice of L21_0 rows -> Lt (transposed), wave0 solves a slice of
// U12 cols (K=64 TRSM over ALL trailing cols) -> M. One 64-float array per thread.
__global__ __launch_bounds__(128) void k_panelA(float* __restrict__ Mall, float* __restrict__ LtAll,
                                                float* __restrict__ logdets, int k0) {
  const int b = blockIdx.x;
  const int sub = blockIdx.y;       // 0..7
  float* __restrict__ M  = Mall  + (size_t)b*MS;
  float* __restrict__ Lt = LtAll + (size_t)b*LTS2;
  const int t = threadIdx.x;
  const int m = NDIM - k0;          // 512,384,256,128
  const int mrem = m - 64;
  const int rs = (mrem + 7) >> 3;   // slice size per sub-block
  __shared__ float T[64][68];       // factored diag0 transposed; recip at [r][66]

  float a[64];
  if (t < 64) {                     // wave0: diag0 LU (duplicated across subs)
    const float* row = M + (size_t)(k0+t)*NDIM + k0;
    #pragma unroll
    for (int c4 = 0; c4 < 16; ++c4) {
      float4 v = *(const float4*)(row + c4*4);
      a[c4*4+0]=v.x; a[c4*4+1]=v.y; a[c4*4+2]=v.z; a[c4*4+3]=v.w;
    }
    float mypiv = 1.f, myrec = 1.f;
    WFact<0>::run(a, t, mypiv, myrec);
    #pragma unroll
    for (int c = 0; c < 64; ++c) T[c][t] = a[c];
    T[t][66] = myrec;
    float v = logf(fabsf(mypiv));
    #pragma unroll
    for (int off = 32; off > 0; off >>= 1) v += __shfl_down(v, off, 64);
    if (sub == 0 && t == 0) logdets[b] = (k0 == 0) ? v : (logdets[b] + v);
  }
  __syncthreads();

  if (mrem > 0) {
    if (t >= 64) {                  // wave1: L21_0 rows slice -> Lt (coalesced transposed)
      const int idx = sub*rs + (t - 64);
      if ((t - 64) < rs && idx < mrem) {
        const int gr = k0 + 64 + idx;
        const float* row = M + (size_t)gr*NDIM + k0;
        #pragma unroll
        for (int c4 = 0; c4 < 16; ++c4) {
          float4 v = *(const float4*)(row + c4*4);
          a[c4*4+0]=v.x; a[c4*4+1]=v.y; a[c4*4+2]=v.z; a[c4*4+3]=v.w;
        }
        SolveStep<0>::run(a, T);
        #pragma unroll
        for (int c = 0; c < 64; ++c) Lt[(size_t)c*NDIM + gr] = a[c];
      }
    } else {                        // wave0: U12 cols slice (K=64 TRSM) -> M
      const int idx = sub*rs + t;
      if (t < rs && idx < mrem) {
        const int col = k0 + 64 + idx;
        float u[64];
        #pragma unroll
        for (int r = 0; r < 64; ++r) u[r] = M[(size_t)(k0+r)*NDIM + col];
        #pragma unroll
        for (int p = 0; p < 63; ++p) {
          const float lv = u[p];
          #pragma unroll
          for (int kk = p+1; kk < 64; ++kk) u[kk] -= T[p][kk] * lv;
        }
        #pragma unroll
        for (int r = 1; r < 64; ++r) M[(size_t)(k0+r)*NDIM + col] = u[r];
      }
    }
  }
}

// ---------- strip update: C[64..m, 64..128) -= L21_0 * U12strip (A from Lt, float4) ----------
__global__ __launch_bounds__(256, 4) void k_strip(float* __restrict__ Mall, const float* __restrict__ LtAll,
                                                  int k0) {
  const int b = blockIdx.y;                 // b slowest -> same-matrix tiles contiguous
  float* __restrict__ M  = Mall  + (size_t)b*MS;
  const float* __restrict__ Lt = LtAll + (size_t)b*LTS2;
  __shared__ float As[64][68];     // As[p][r] = L21_0[rowbase+r][p] = Lt[p][k0+rowbase+r]
  __shared__ float Bs[64][68];     // Bs[p][c] = U12strip[p][c]
  const int tid = threadIdx.x;
  const int tx = tid & 15, ty = tid >> 4;
  const int rowbase = 64 + blockIdx.x*64;
  #pragma unroll
  for (int i = 0; i < 4; ++i) {
    const int q = tid + 256*i, qr = q >> 4, qf = q & 15;
    *(float4*)&As[qr][qf*4] = *(const float4*)&Lt[(size_t)qr*NDIM + (k0+rowbase) + qf*4];
    *(float4*)&Bs[qr][qf*4] = *(const float4*)&M[(size_t)(k0+qr)*NDIM + (k0+64) + qf*4];
  }
  float* Crow = M + (size_t)(k0+rowbase+ty*4)*NDIM + (k0+64+tx*4);
  float4 c0 = *(float4*)(Crow + 0*NDIM);
  float4 c1 = *(float4*)(Crow + 1*NDIM);
  float4 c2 = *(float4*)(Crow + 2*NDIM);
  float4 c3 = *(float4*)(Crow + 3*NDIM);
  __syncthreads();
  #pragma unroll
  for (int p = 0; p < 64; ++p) {
    const float4 av = *(const float4*)&As[p][ty*4];
    const float4 bv = *(const float4*)&Bs[p][tx*4];
    c0.x -= av.x*bv.x; c0.y -= av.x*bv.y; c0.z -= av.x*bv.z; c0.w -= av.x*bv.w;
    c1.x -= av.y*bv.x; c1.y -= av.y*bv.y; c1.z -= av.y*bv.z; c1.w -= av.y*bv.w;
    c2.x -= av.z*bv.x; c2.y -= av.z*bv.y; c2.z -= av.z*bv.z; c2.w -= av.z*bv.w;
    c3.x -= av.w*bv.x; c3.y -= av.w*bv.y; c3.z -= av.w*bv.z; c3.w -= av.w*bv.w;
  }
  *(float4*)(Crow + 0*NDIM) = c0;
  *(float4*)(Crow + 1*NDIM) = c1;
  *(float4*)(Crow + 2*NDIM) = c2;
  *(float4*)(Crow + 3*NDIM) = c3;
}

// ---------- panel B, 8-way split: diag1 LU (dup) + Ls2 from Lt; wave1 = L21_1 rows
// slice -> Lt, wave0 = far cols 3-stage TRSM slice -> M ----------
__global__ __launch_bounds__(128) void k_panelB(float* __restrict__ Mall, float* __restrict__ LtAll,
                                                float* __restrict__ logdets, int k0, int ncols) {
  const int b = blockIdx.x;
  const int sub = blockIdx.y;
  float* __restrict__ M  = Mall  + (size_t)b*MS;
  float* __restrict__ Lt = LtAll + (size_t)b*LTS2;
  const int t = threadIdx.x;
  const int rs = (ncols + 7) >> 3;
  __shared__ float T[64][68];       // factored diag1 transposed; recip at [r][66]
  __shared__ float Ls2[64][68];     // Ls2[p][r] = L21strip[64+r][p] = Lt[p][k0+64+r]

  float s[64];
  if (t < 64) {                     // wave0: diag1 LU (strip-updated rows)
    const float* row = M + (size_t)(k0+64+t)*NDIM + (k0+64);
    #pragma unroll
    for (int c4 = 0; c4 < 16; ++c4) {
      float4 v = *(const float4*)(row + c4*4);
      s[c4*4+0]=v.x; s[c4*4+1]=v.y; s[c4*4+2]=v.z; s[c4*4+3]=v.w;
    }
    float mypiv = 1.f, myrec = 1.f;
    WFact<0>::run(s, t, mypiv, myrec);
    #pragma unroll
    for (int c = 0; c < 64; ++c) T[c][t] = s[c];
    T[t][66] = myrec;
    float v = logf(fabsf(mypiv));
    #pragma unroll
    for (int off = 32; off > 0; off >>= 1) v += __shfl_down(v, off, 64);
    if (sub == 0 && t == 0) logdets[b] += v;
  } else {                          // wave1: stage Ls2 from Lt (coalesced per c)
    const int r = t - 64;
    #pragma unroll
    for (int c = 0; c < 64; ++c) Ls2[c][r] = Lt[(size_t)c*NDIM + (k0+64+r)];
  }
  __syncthreads();

  if (ncols > 0) {
    if (t >= 64) {                  // wave1: L21_1 rows slice -> Lt cols 64..127
      const int idx = sub*rs + (t - 64);
      if ((t - 64) < rs && idx < ncols) {
        const int gr = k0 + 128 + idx;
        const float* row = M + (size_t)gr*NDIM + (k0+64);
        #pragma unroll
        for (int c4 = 0; c4 < 16; ++c4) {
          float4 v = *(const float4*)(row + c4*4);
          s[c4*4+0]=v.x; s[c4*4+1]=v.y; s[c4*4+2]=v.z; s[c4*4+3]=v.w;
        }
        SolveStep<0>::run(s, T);
        #pragma unroll
        for (int c = 0; c < 64; ++c) Lt[(size_t)(64+c)*NDIM + gr] = s[c];
      }
    } else {                        // wave0: far cols, u1 -= L21strip*u0 then K=64 TRSM
      const int idx = sub*rs + t;
      if (t < rs && idx < ncols) {
        const int col = k0 + 128 + idx;
        float u[64];
        #pragma unroll
        for (int r = 0; r < 64; ++r) u[r] = M[(size_t)(k0+64+r)*NDIM + col];
        #pragma unroll
        for (int p = 0; p < 64; ++p) {
          const float up = M[(size_t)(k0+p)*NDIM + col];  // U12_0, written by k_panelA
          #pragma unroll
          for (int r = 0; r < 64; ++r) u[r] -= Ls2[p][r] * up;
        }
        #pragma unroll
        for (int p = 0; p < 63; ++p) {
          const float lv = u[p];
          #pragma unroll
          for (int kk = p+1; kk < 64; ++kk) u[kk] -= T[p][kk] * lv;
        }
        #pragma unroll
        for (int r = 0; r < 64; ++r) M[(size_t)(k0+64+r)*NDIM + col] = u[r];
      }
    }
  }
}

// ---------- trailing update: C -= L21 * U12, K=128, A from Lt (float4, no scatter) ----------
__global__ __launch_bounds__(256, 4) void k_gemm2(float* __restrict__ Mall, const float* __restrict__ LtAll,
                                                  int k0) {
  const int b = blockIdx.z;                 // b slowest -> L2 reuse of Lt/M panels
  float* __restrict__ M  = Mall  + (size_t)b*MS;
  const float* __restrict__ Lt = LtAll + (size_t)b*LTS2;
  __shared__ float As[64][68];     // As[p][r] = L21[rowbase+r][p] = Lt[p][k0+rowbase+r]
  __shared__ float Bs[64][68];     // Bs[p][c] = U12[p][c]
  const int tid = threadIdx.x;
  const int tx = tid & 15, ty = tid >> 4;
  const int rowbase = 128 + blockIdx.x*64;
  const int colbase = 128 + blockIdx.y*64;
  float* Crow = M + (size_t)(k0+rowbase+ty*4)*NDIM + (k0+colbase+tx*4);
  float4 c0 = *(float4*)(Crow + 0*NDIM);
  float4 c1 = *(float4*)(Crow + 1*NDIM);
  float4 c2 = *(float4*)(Crow + 2*NDIM);
  float4 c3 = *(float4*)(Crow + 3*NDIM);
  #pragma unroll
  for (int i = 0; i < 4; ++i) {
    const int q = tid + 256*i, qr = q >> 4, qf = q & 15;
    *(float4*)&As[qr][qf*4] = *(const float4*)&Lt[(size_t)qr*NDIM + (k0+rowbase) + qf*4];
    *(float4*)&Bs[qr][qf*4] = *(const float4*)&M[(size_t)(k0+qr)*NDIM + (k0+colbase) + qf*4];
  }
  __syncthreads();
  float4 ra[4], rb[4];
  #pragma unroll
  for (int i = 0; i < 4; ++i) {
    const int q = tid + 256*i, qr = q >> 4, qf = q & 15;
    ra[i] = *(const float4*)&Lt[(size_t)(64+qr)*NDIM + (k0+rowbase) + qf*4];
    rb[i] = *(const float4*)&M[(size_t)(k0+64+qr)*NDIM + (k0+colbase) + qf*4];
  }
  #pragma unroll
  for (int p = 0; p < 64; ++p) {
    const float4 av = *(const float4*)&As[p][ty*4];
    const float4 bv = *(const float4*)&Bs[p][tx*4];
    c0.x -= av.x*bv.x; c0.y -= av.x*bv.y; c0.z -= av.x*bv.z; c0.w -= av.x*bv.w;
    c1.x -= av.y*bv.x; c1.y -= av.y*bv.y; c1.z -= av.y*bv.z; c1.w -= av.y*bv.w;
    c2.x -= av.z*bv.x; c2.y -= av.z*bv.y; c2.z -= av.z*bv.z; c2.w -= av.z*bv.w;
    c3.x -= av.w*bv.x; c3.y -= av.w*bv.y; c3.z -= av.w*bv.z; c3.w -= av.w*bv.w;
  }
  __syncthreads();
  #pragma unroll
  for (int i = 0; i < 4; ++i) {
    const int q = tid + 256*i, qr = q >> 4, qf = q & 15;
    *(float4*)&As[qr][qf*4] = ra[i];
    *(float4*)&Bs[qr][qf*4] = rb[i];
  }
  __syncthreads();
  #pragma unroll
  for (int p = 0; p < 64; ++p) {
    const float4 av = *(const float4*)&As[p][ty*4];
    const float4 bv = *(const float4*)&Bs[p][tx*4];
    c0.x -= av.x*bv.x; c0.y -= av.x*bv.y; c0.z -= av.x*bv.z; c0.w -= av.x*bv.w;
    c1.x -= av.y*bv.x; c1.y -= av.y*bv.y; c1.z -= av.y*bv.z; c1.w -= av.y*bv.w;
    c2.x -= av.z*bv.x; c2.y -= av.z*bv.y; c2.z -= av.z*bv.z; c2.w -= av.z*bv.w;
    c3.x -= av.w*bv.x; c3.y -= av.w*bv.y; c3.z -= av.w*bv.z; c3.w -= av.w*bv.w;
  }
  *(float4*)(Crow + 0*NDIM) = c0;
  *(float4*)(Crow + 1*NDIM) = c1;
  *(float4*)(Crow + 2*NDIM) = c2;
  *(float4*)(Crow + 3*NDIM) = c3;
}

// ---------- final combine ----------
__global__ void k_final(const float* __restrict__ logPr, const float* __restrict__ logdets,
                        float* __restrict__ out) {
  int t = threadIdx.x;
  if (t < NB) out[t] = logPr[t] + logdets[t] - logdets[NB];
}

extern "C" void kernel_launch(void* const* d_in, const int* in_sizes, int n_in,
                              void* d_out, int out_size, void* d_ws, size_t ws_size,
                              hipStream_t stream) {
  const int*   x  = (const int*)  d_in[0];
  const float* W  = (const float*)d_in[1];
  const float* Vc = (const float*)d_in[2];
  const float* Ec = (const float*)d_in[3];
  float* out = (float*)d_out;
  float* ws  = (float*)d_ws;
  (void)in_sizes; (void)n_in; (void)out_size; (void)ws_size;  // needs ~167 MiB of ws

  float* Mat = ws + OFF_MAT;
  float* Lt  = ws + OFF_LT;
  float* Ld  = ws + OFF_LD;

  k_prep<<<1024, 256, 0, stream>>>(W, Vc, Ec, ws + OFF_WM, ws + OFF_E);
  k_Pr  <<<NB,   256, 0, stream>>>(x, Vc, ws + OFF_IPR, ws + OFF_LPR);
  dim3 gb(NMAT, 64);
  k_build<<<gb, 512, 0, stream>>>(x, ws + OFF_E, ws + OFF_WM, ws + OFF_IPR, Mat);

  for (int S = 0; S < 4; ++S) {
    const int k0 = S*128;
    const int m = NDIM - k0;
    const int mrem = m - 64;
    const int ncols = m - 128;
    dim3 gpa(NMAT, 8);
    k_panelA<<<gpa, 128, 0, stream>>>(Mat, Lt, Ld, k0);
    dim3 gs(mrem/64, NMAT);
    k_strip<<<gs, 256, 0, stream>>>(Mat, Lt, k0);
    dim3 gpb(NMAT, (ncols > 0) ? 8 : 1);
    k_panelB<<<gpb, 128, 0, stream>>>(Mat, Lt, Ld, k0, ncols);
    if (ncols > 0) {
      const int nt = ncols/64;
      dim3 gg(nt, nt, NMAT);
      k_gemm2<<<gg, 256, 0, stream>>>(Mat, Lt, k0);
    }
  }
  k_final<<<1, 128, 0, stream>>>(ws + OFF_LPR, Ld, out);
}

// Round 10
// 614.801 us; speedup vs baseline: 1.4421x; 1.4421x over previous
//
#include <hip/hip_runtime.h>
#include <hip/hip_bf16.h>
#include <math.h>

#define NDIM 512
#define NB   128
#define NMAT 129
#define EPSF 1e-7f
#define MS  ((size_t)262144)   // matrix stride (floats) = 512*512
#define LTS ((size_t)32768)    // Lt stride per matrix (floats) = 64*512
#define PSTR ((size_t)524288)  // E2 plane stride (floats) = 512*512*2

// workspace layout (float offsets)
#define OFF_E   ((size_t)0)                    // 1,048,576
#define OFF_WM  ((size_t)1048576)              // 262,144
#define OFF_IPR ((size_t)1310720)              // 65,536
#define OFF_LPR ((size_t)1376256)              // 128
#define OFF_LD  ((size_t)1376384)              // 129
#define OFF_MAT ((size_t)1377792)              // 129*262144
#define OFF_LT  ((size_t)(OFF_MAT + (size_t)NMAT*MS))  // 129*32768 -> ~158 MB total

__device__ __forceinline__ float rdlane(float v, int l) {
  return __uint_as_float((unsigned)__builtin_amdgcn_readlane((int)__float_as_uint(v), l));
}

// ---------- fused Wm + E-IPF (verified R8/R9, absmax 0) ----------
__global__ __launch_bounds__(256) void k_prep(const float* __restrict__ W, const float* __restrict__ Vc,
                                              const float* __restrict__ Ec, float* __restrict__ Wm,
                                              float* __restrict__ E2) {
  int idx = blockIdx.x * 256 + threadIdx.x;   // i*512 + j
  int i = idx >> 9, j = idx & 511;
  float wv = 0.f;
  if (i > j)      wv = 1.f / (1.f + expf(-W[i*NDIM + j]));
  else if (i < j) wv = 1.f / (1.f + expf(-W[j*NDIM + i]));
  Wm[idx] = wv;
  float vi0 = Vc[2*i], vi1 = Vc[2*i+1];
  float mi = fmaxf(vi0, vi1);
  float ei0 = expf(vi0 - mi), ei1 = expf(vi1 - mi);
  float si = ei0 + ei1;
  float A0 = ei0 / si, A1 = ei1 / si;
  float vj0 = Vc[2*j], vj1 = Vc[2*j+1];
  float mj = fmaxf(vj0, vj1);
  float ej0 = expf(vj0 - mj), ej1 = expf(vj1 - mj);
  float sj = ej0 + ej1;
  float B0 = ej0 / sj, B1 = ej1 / sj;
  float4 ec = reinterpret_cast<const float4*>(Ec)[idx];
  float e00 = expf(ec.x), e01 = expf(ec.y), e10 = expf(ec.z), e11 = expf(ec.w);
  float s = e00 + e01 + e10 + e11;
  float inv = 1.f / s;
  e00 *= inv; e01 *= inv; e10 *= inv; e11 *= inv;
  for (int t = 0; t < 10; ++t) {
    float rm0 = e00 + e01 + EPSF, rm1 = e10 + e11 + EPSF;
    float cm0 = e00 + e10 + EPSF, cm1 = e01 + e11 + EPSF;
    float f0 = A0 / rm0, f1 = A1 / rm1;
    e00 *= f0; e01 *= f0; e10 *= f1; e11 *= f1;
    float g0 = B0 / cm0, g1 = B1 / cm1;
    e00 *= g0; e10 *= g0; e01 *= g1; e11 *= g1;
    float ss = e00 + e01 + e10 + e11 + EPSF;
    float iv = 1.f / ss;
    e00 *= iv; e01 *= iv; e10 *= iv; e11 *= iv;
  }
  if (i == j) { e00 = 0.f; e01 = 0.f; e10 = 0.f; e11 = 0.f; }
  e00 = fminf(fmaxf(e00, 0.f), 1.f);
  e01 = fminf(fmaxf(e01, 0.f), 1.f);
  e10 = fminf(fmaxf(e10, 0.f), 1.f);
  e11 = fminf(fmaxf(e11, 0.f), 1.f);
  reinterpret_cast<float2*>(E2)[idx]        = make_float2(e00, e01);
  reinterpret_cast<float2*>(E2 + PSTR)[idx] = make_float2(e10, e11);
}

// ---------- Pr, invPr, sum(log Pr) (V inline; verified R8/R9) ----------
__global__ __launch_bounds__(256) void k_Pr(const int* __restrict__ x, const float* __restrict__ Vc,
                                            float* __restrict__ invPr, float* __restrict__ logPr) {
  const int b = blockIdx.x;
  const int tid = threadIdx.x;
  float acc = 0.f;
  for (int ii = tid; ii < NDIM; ii += 256) {
    const int xv = x[b*NDIM + ii];
    float v0 = Vc[2*ii], v1 = Vc[2*ii+1];
    float mx = fmaxf(v0, v1);
    float e0 = expf(v0 - mx), e1 = expf(v1 - mx);
    float s = e0 + e1;
    const float p = xv ? (e1 / s) : (e0 / s);
    invPr[b*NDIM + ii] = 1.f / p;
    acc += logf(p);
  }
  for (int off = 32; off > 0; off >>= 1) acc += __shfl_down(acc, off, 64);
  __shared__ float sw[4];
  if ((tid & 63) == 0) sw[tid >> 6] = acc;
  __syncthreads();
  if (tid == 0) logPr[b] = sw[0] + sw[1] + sw[2] + sw[3];
}

// ---------- build full 512x512 embedded minors: row0 = e0, col0 = 0 ----------
__global__ __launch_bounds__(512) void k_build(const int* __restrict__ x, const float* __restrict__ E2,
                                               const float* __restrict__ Wm, const float* __restrict__ invPr,
                                               float* __restrict__ Mall) {
  const int b = blockIdx.x;
  const int i = blockIdx.y*8 + (threadIdx.x >> 6);
  const int lane = threadIdx.x & 63;
  const int j0 = lane << 3;

  const float4 w0 = *(const float4*)(Wm + (size_t)i*NDIM + j0);
  const float4 w1 = *(const float4*)(Wm + (size_t)i*NDIM + j0 + 4);
  float wp[8];
  if (b < NB) {
    const int   xi   = x[b*NDIM + i];
    const float ipri = invPr[b*NDIM + i];
    const int4  xa = *(const int4*)(x + b*NDIM + j0);
    const int4  xb = *(const int4*)(x + b*NDIM + j0 + 4);
    const float4 pa = *(const float4*)(invPr + b*NDIM + j0);
    const float4 pb = *(const float4*)(invPr + b*NDIM + j0 + 4);
    const float* pl = E2 + (size_t)xi*PSTR + ((size_t)i*NDIM + j0)*2;
    const float4 ea = *(const float4*)(pl);
    const float4 eb = *(const float4*)(pl + 4);
    const float4 ec = *(const float4*)(pl + 8);
    const float4 ed = *(const float4*)(pl + 12);
    wp[0] = w0.x * (xa.x ? ea.y : ea.x) * pa.x;
    wp[1] = w0.y * (xa.y ? ea.w : ea.z) * pa.y;
    wp[2] = w0.z * (xa.z ? eb.y : eb.x) * pa.z;
    wp[3] = w0.w * (xa.w ? eb.w : eb.z) * pa.w;
    wp[4] = w1.x * (xb.x ? ec.y : ec.x) * pb.x;
    wp[5] = w1.y * (xb.y ? ec.w : ec.z) * pb.y;
    wp[6] = w1.z * (xb.z ? ed.y : ed.x) * pb.z;
    wp[7] = w1.w * (xb.w ? ed.w : ed.z) * pb.w;
    #pragma unroll
    for (int k = 0; k < 8; ++k) wp[k] *= ipri;
  } else {
    wp[0]=w0.x; wp[1]=w0.y; wp[2]=w0.z; wp[3]=w0.w;
    wp[4]=w1.x; wp[5]=w1.y; wp[6]=w1.z; wp[7]=w1.w;
  }
  float s = ((wp[0]+wp[1])+(wp[2]+wp[3])) + ((wp[4]+wp[5])+(wp[6]+wp[7]));
  #pragma unroll
  for (int off = 32; off > 0; off >>= 1) s += __shfl_xor(s, off, 64);

  float o[8];
  #pragma unroll
  for (int k = 0; k < 8; ++k) o[k] = -wp[k];
  if (i == 0) {
    #pragma unroll
    for (int k = 0; k < 8; ++k) o[k] = 0.f;
    if (lane == 0) o[0] = 1.f;
  } else {
    if (lane == 0) o[0] = 0.f;
    #pragma unroll
    for (int k = 0; k < 8; ++k)
      if (j0 + k == i) o[k] = s;
  }
  float* dst = Mall + (size_t)b*MS + (size_t)i*NDIM + j0;
  *(float4*)(dst)   = make_float4(o[0],o[1],o[2],o[3]);
  *(float4*)(dst+4) = make_float4(o[4],o[5],o[6],o[7]);
}

// ---------- single-wave 64x64 LU via readlane (proven R3) ----------
template<int KK>
struct WFact {
  static __device__ __forceinline__ void run(float (&a)[64], const int lane,
                                             float& mypiv, float& myrec) {
    const float piv = rdlane(a[KK], KK);
    const float rec = 1.0f / piv;
    if (lane == KK) { mypiv = piv; myrec = rec; }
    if (lane > KK) {
      const float l = a[KK] * rec;
      a[KK] = l;
      #pragma unroll
      for (int c = KK + 1; c < 64; ++c)
        a[c] -= l * rdlane(a[c], KK);
    }
    WFact<KK + 1>::run(a, lane, mypiv, myrec);
  }
};
template<>
struct WFact<64> {
  static __device__ __forceinline__ void run(float (&)[64], int, float&, float&) {}
};

// ---------- L21 row triangular solve, float4 LDS reads, exact ascending-p order ----------
template<int C>
struct SolveStep {
  static __device__ __forceinline__ void run(float (&a)[64], const float (*T)[68]) {
    const float* Trow = T[C];
    float acc = a[C];
    #pragma unroll
    for (int p4 = 0; p4 + 4 <= C; p4 += 4) {
      const float4 tv = *(const float4*)(Trow + p4);
      acc -= a[p4+0] * tv.x;
      acc -= a[p4+1] * tv.y;
      acc -= a[p4+2] * tv.z;
      acc -= a[p4+3] * tv.w;
    }
    #pragma unroll
    for (int p = C & ~3; p < C; ++p) acc -= a[p] * Trow[p];
    a[C] = acc * Trow[66];                    // * 1/U11[C][C]
    SolveStep<C + 1>::run(a, T);
  }
};
template<>
struct SolveStep<64> {
  static __device__ __forceinline__ void run(float (&)[64], const float (*)[68]) {}
};

// ---------- panel (R3 structure): wave0 wave-LU, then L21 solve + K=64 TRSM ----------
// LDS-pressure fix: SolveStep and TRSM inner loops use ds_read_b128 (4x fewer LDS ops);
// kk-order inside TRSM is bitwise-irrelevant (one FMA per (kk,p), p-order preserved).
__global__ __launch_bounds__(512) void k_panel(float* __restrict__ Mall, float* __restrict__ Lt,
                                               float* __restrict__ logdets, int k0, int mrem) {
  const int b = blockIdx.x;
  float* __restrict__ M = Mall + (size_t)b*MS;
  float* __restrict__ L = Lt + (size_t)b*LTS;
  const int t = threadIdx.x;
  const int m = NDIM - k0;          // 512,448,...,64
  __shared__ __align__(16) float T[64][68];   // T[c][r] = factored_block[r][c]; recip at [c][66]

  float a[64];
  if (t < m) {
    const float* row = M + (size_t)(k0+t)*NDIM + k0;
    #pragma unroll
    for (int c4 = 0; c4 < 16; ++c4) {
      float4 v = *(const float4*)(row + c4*4);
      a[c4*4+0]=v.x; a[c4*4+1]=v.y; a[c4*4+2]=v.z; a[c4*4+3]=v.w;
    }
  }

  if (t < 64) {
    float mypiv = 1.f, myrec = 1.f;
    WFact<0>::run(a, t, mypiv, myrec);
    #pragma unroll
    for (int c = 0; c < 64; ++c) T[c][t] = a[c];
    T[t][66] = myrec;
    float v = logf(fabsf(mypiv));
    #pragma unroll
    for (int off = 32; off > 0; off >>= 1) v += __shfl_down(v, off, 64);
    if (t == 0) logdets[b] = (k0 == 0) ? v : (logdets[b] + v);
  }
  __syncthreads();

  if (mrem > 0) {
    // L21 rows: barrier-free solve, write transposed panel (coalesced per c)
    if (t >= 64 && t < m) {
      SolveStep<0>::run(a, T);
      #pragma unroll
      for (int c = 0; c < 64; ++c) L[(size_t)c*NDIM + t] = a[c];
    }
    // TRSM: U12 = L11^{-1} A12, one column per thread (mrem <= 448 < 512)
    if (t < mrem) {
      const int col = k0 + 64 + t;
      float u[64];
      #pragma unroll
      for (int r = 0; r < 64; ++r) u[r] = M[(size_t)(k0+r)*NDIM + col];
      #pragma unroll
      for (int p = 0; p < 63; ++p) {
        const float lv = u[p];
        const float* Trow = T[p];
        const int kk0 = p + 1;
        const int kkA = (p + 4) & ~3;          // align-up of kk0
        #pragma unroll
        for (int kk = kk0; kk < kkA; ++kk) u[kk] -= Trow[kk] * lv;
        #pragma unroll
        for (int kk4 = kkA; kk4 < 64; kk4 += 4) {
          const float4 tv = *(const float4*)(Trow + kk4);
          u[kk4+0] -= tv.x * lv;
          u[kk4+1] -= tv.y * lv;
          u[kk4+2] -= tv.z * lv;
          u[kk4+3] -= tv.w * lv;
        }
      }
      #pragma unroll
      for (int r = 1; r < 64; ++r) M[(size_t)(k0+r)*NDIM + col] = u[r];
    }
  }
}

// ---------- trailing update (R3 exact): C -= L21 * U12, 64x64 tile, 4x4/thread ----------
__global__ __launch_bounds__(256, 4) void k_gemm(float* __restrict__ Mall, const float* __restrict__ Lt,
                                                 int k0) {
  const int b = blockIdx.x;
  float* __restrict__ M = Mall + (size_t)b*MS;
  const float* __restrict__ L = Lt + (size_t)b*LTS;
  __shared__ __align__(16) float As[64][68];   // As[p][r] = L21[r][p]
  __shared__ __align__(16) float Bs[64][68];   // Bs[p][c] = U12[p][c]
  const int tid = threadIdx.x;
  const int tx = tid & 15, ty = tid >> 4;
  const int rowbase = 64 + blockIdx.y*64;
  const int colbase = 64 + blockIdx.z*64;
  #pragma unroll
  for (int i = 0; i < 4; ++i) {
    int q = tid + 256*i;           // 1024 float4
    int p = q >> 4, f = q & 15;
    *(float4*)&As[p][f*4] = *(const float4*)&L[(size_t)p*NDIM + rowbase + f*4];
    *(float4*)&Bs[p][f*4] = *(const float4*)&M[(size_t)(k0+p)*NDIM + (k0+colbase) + f*4];
  }
  float* Crow = M + (size_t)(k0+rowbase+ty*4)*NDIM + (k0+colbase+tx*4);
  float4 c0 = *(float4*)(Crow + 0*NDIM);
  float4 c1 = *(float4*)(Crow + 1*NDIM);
  float4 c2 = *(float4*)(Crow + 2*NDIM);
  float4 c3 = *(float4*)(Crow + 3*NDIM);
  __syncthreads();
  #pragma unroll
  for (int p = 0; p < 64; ++p) {
    const float4 av = *(const float4*)&As[p][ty*4];
    const float4 bv = *(const float4*)&Bs[p][tx*4];
    c0.x -= av.x*bv.x; c0.y -= av.x*bv.y; c0.z -= av.x*bv.z; c0.w -= av.x*bv.w;
    c1.x -= av.y*bv.x; c1.y -= av.y*bv.y; c1.z -= av.y*bv.z; c1.w -= av.y*bv.w;
    c2.x -= av.z*bv.x; c2.y -= av.z*bv.y; c2.z -= av.z*bv.z; c2.w -= av.z*bv.w;
    c3.x -= av.w*bv.x; c3.y -= av.w*bv.y; c3.z -= av.w*bv.z; c3.w -= av.w*bv.w;
  }
  *(float4*)(Crow + 0*NDIM) = c0;
  *(float4*)(Crow + 1*NDIM) = c1;
  *(float4*)(Crow + 2*NDIM) = c2;
  *(float4*)(Crow + 3*NDIM) = c3;
}

// ---------- final combine ----------
__global__ void k_final(const float* __restrict__ logPr, const float* __restrict__ logdets,
                        float* __restrict__ out) {
  int t = threadIdx.x;
  if (t < NB) out[t] = logPr[t] + logdets[t] - logdets[NB];
}

extern "C" void kernel_launch(void* const* d_in, const int* in_sizes, int n_in,
                              void* d_out, int out_size, void* d_ws, size_t ws_size,
                              hipStream_t stream) {
  const int*   x  = (const int*)  d_in[0];
  const float* W  = (const float*)d_in[1];
  const float* Vc = (const float*)d_in[2];
  const float* Ec = (const float*)d_in[3];
  float* out = (float*)d_out;
  float* ws  = (float*)d_ws;
  (void)in_sizes; (void)n_in; (void)out_size; (void)ws_size;  // needs ~158 MiB of ws

  float* Mat = ws + OFF_MAT;
  float* Lt  = ws + OFF_LT;
  float* Ld  = ws + OFF_LD;

  k_prep<<<1024, 256, 0, stream>>>(W, Vc, Ec, ws + OFF_WM, ws + OFF_E);
  k_Pr  <<<NB,   256, 0, stream>>>(x, Vc, ws + OFF_IPR, ws + OFF_LPR);
  dim3 gb(NMAT, 64);
  k_build<<<gb, 512, 0, stream>>>(x, ws + OFF_E, ws + OFF_WM, ws + OFF_IPR, Mat);

  for (int s = 0; s < 8; ++s) {
    const int k0 = s*64;
    const int mrem = NDIM - k0 - 64;
    k_panel<<<NMAT, 512, 0, stream>>>(Mat, Lt, Ld, k0, mrem);
    if (mrem > 0) {
      const int nt = mrem/64;
      dim3 gg(NMAT, nt, nt);
      k_gemm<<<gg, 256, 0, stream>>>(Mat, Lt, k0);
    }
  }
  k_final<<<1, 128, 0, stream>>>(ws + OFF_LPR, Ld, out);
}

// Round 11
// 564.473 us; speedup vs baseline: 1.5707x; 1.0892x over previous
//
#include <hip/hip_runtime.h>
#include <hip/hip_bf16.h>
#include <math.h>

#define NDIM 512
#define NB   128
#define NMAT 129
#define EPSF 1e-7f
#define MS  ((size_t)262144)   // matrix stride (floats) = 512*512
#define LTS ((size_t)32768)    // Lt stride per matrix (floats) = 64*512
#define PSTR ((size_t)524288)  // E2 plane stride (floats) = 512*512*2

// workspace layout (float offsets)
#define OFF_E   ((size_t)0)                    // 1,048,576
#define OFF_WM  ((size_t)1048576)              // 262,144
#define OFF_IPR ((size_t)1310720)              // 65,536
#define OFF_LPR ((size_t)1376256)              // 128
#define OFF_LD  ((size_t)1376384)              // 129
#define OFF_MAT ((size_t)1377792)              // 129*262144
#define OFF_LT  ((size_t)(OFF_MAT + (size_t)NMAT*MS))  // 129*32768 -> ~158 MB total

__device__ __forceinline__ float rdlane(float v, int l) {
  return __uint_as_float((unsigned)__builtin_amdgcn_readlane((int)__float_as_uint(v), l));
}

// ---------- fused Wm + E-IPF (verified, absmax 0) ----------
__global__ __launch_bounds__(256) void k_prep(const float* __restrict__ W, const float* __restrict__ Vc,
                                              const float* __restrict__ Ec, float* __restrict__ Wm,
                                              float* __restrict__ E2) {
  int idx = blockIdx.x * 256 + threadIdx.x;   // i*512 + j
  int i = idx >> 9, j = idx & 511;
  float wv = 0.f;
  if (i > j)      wv = 1.f / (1.f + expf(-W[i*NDIM + j]));
  else if (i < j) wv = 1.f / (1.f + expf(-W[j*NDIM + i]));
  Wm[idx] = wv;
  float vi0 = Vc[2*i], vi1 = Vc[2*i+1];
  float mi = fmaxf(vi0, vi1);
  float ei0 = expf(vi0 - mi), ei1 = expf(vi1 - mi);
  float si = ei0 + ei1;
  float A0 = ei0 / si, A1 = ei1 / si;
  float vj0 = Vc[2*j], vj1 = Vc[2*j+1];
  float mj = fmaxf(vj0, vj1);
  float ej0 = expf(vj0 - mj), ej1 = expf(vj1 - mj);
  float sj = ej0 + ej1;
  float B0 = ej0 / sj, B1 = ej1 / sj;
  float4 ec = reinterpret_cast<const float4*>(Ec)[idx];
  float e00 = expf(ec.x), e01 = expf(ec.y), e10 = expf(ec.z), e11 = expf(ec.w);
  float s = e00 + e01 + e10 + e11;
  float inv = 1.f / s;
  e00 *= inv; e01 *= inv; e10 *= inv; e11 *= inv;
  for (int t = 0; t < 10; ++t) {
    float rm0 = e00 + e01 + EPSF, rm1 = e10 + e11 + EPSF;
    float cm0 = e00 + e10 + EPSF, cm1 = e01 + e11 + EPSF;
    float f0 = A0 / rm0, f1 = A1 / rm1;
    e00 *= f0; e01 *= f0; e10 *= f1; e11 *= f1;
    float g0 = B0 / cm0, g1 = B1 / cm1;
    e00 *= g0; e10 *= g0; e01 *= g1; e11 *= g1;
    float ss = e00 + e01 + e10 + e11 + EPSF;
    float iv = 1.f / ss;
    e00 *= iv; e01 *= iv; e10 *= iv; e11 *= iv;
  }
  if (i == j) { e00 = 0.f; e01 = 0.f; e10 = 0.f; e11 = 0.f; }
  e00 = fminf(fmaxf(e00, 0.f), 1.f);
  e01 = fminf(fmaxf(e01, 0.f), 1.f);
  e10 = fminf(fmaxf(e10, 0.f), 1.f);
  e11 = fminf(fmaxf(e11, 0.f), 1.f);
  reinterpret_cast<float2*>(E2)[idx]        = make_float2(e00, e01);
  reinterpret_cast<float2*>(E2 + PSTR)[idx] = make_float2(e10, e11);
}

// ---------- Pr, invPr, sum(log Pr) (V inline; verified) ----------
__global__ __launch_bounds__(256) void k_Pr(const int* __restrict__ x, const float* __restrict__ Vc,
                                            float* __restrict__ invPr, float* __restrict__ logPr) {
  const int b = blockIdx.x;
  const int tid = threadIdx.x;
  float acc = 0.f;
  for (int ii = tid; ii < NDIM; ii += 256) {
    const int xv = x[b*NDIM + ii];
    float v0 = Vc[2*ii], v1 = Vc[2*ii+1];
    float mx = fmaxf(v0, v1);
    float e0 = expf(v0 - mx), e1 = expf(v1 - mx);
    float s = e0 + e1;
    const float p = xv ? (e1 / s) : (e0 / s);
    invPr[b*NDIM + ii] = 1.f / p;
    acc += logf(p);
  }
  for (int off = 32; off > 0; off >>= 1) acc += __shfl_down(acc, off, 64);
  __shared__ float sw[4];
  if ((tid & 63) == 0) sw[tid >> 6] = acc;
  __syncthreads();
  if (tid == 0) logPr[b] = sw[0] + sw[1] + sw[2] + sw[3];
}

// ---------- build full 512x512 embedded minors: row0 = e0, col0 = 0 ----------
__global__ __launch_bounds__(512) void k_build(const int* __restrict__ x, const float* __restrict__ E2,
                                               const float* __restrict__ Wm, const float* __restrict__ invPr,
                                               float* __restrict__ Mall) {
  const int b = blockIdx.x;
  const int i = blockIdx.y*8 + (threadIdx.x >> 6);
  const int lane = threadIdx.x & 63;
  const int j0 = lane << 3;

  const float4 w0 = *(const float4*)(Wm + (size_t)i*NDIM + j0);
  const float4 w1 = *(const float4*)(Wm + (size_t)i*NDIM + j0 + 4);
  float wp[8];
  if (b < NB) {
    const int   xi   = x[b*NDIM + i];
    const float ipri = invPr[b*NDIM + i];
    const int4  xa = *(const int4*)(x + b*NDIM + j0);
    const int4  xb = *(const int4*)(x + b*NDIM + j0 + 4);
    const float4 pa = *(const float4*)(invPr + b*NDIM + j0);
    const float4 pb = *(const float4*)(invPr + b*NDIM + j0 + 4);
    const float* pl = E2 + (size_t)xi*PSTR + ((size_t)i*NDIM + j0)*2;
    const float4 ea = *(const float4*)(pl);
    const float4 eb = *(const float4*)(pl + 4);
    const float4 ec = *(const float4*)(pl + 8);
    const float4 ed = *(const float4*)(pl + 12);
    wp[0] = w0.x * (xa.x ? ea.y : ea.x) * pa.x;
    wp[1] = w0.y * (xa.y ? ea.w : ea.z) * pa.y;
    wp[2] = w0.z * (xa.z ? eb.y : eb.x) * pa.z;
    wp[3] = w0.w * (xa.w ? eb.w : eb.z) * pa.w;
    wp[4] = w1.x * (xb.x ? ec.y : ec.x) * pb.x;
    wp[5] = w1.y * (xb.y ? ec.w : ec.z) * pb.y;
    wp[6] = w1.z * (xb.z ? ed.y : ed.x) * pb.z;
    wp[7] = w1.w * (xb.w ? ed.w : ed.z) * pb.w;
    #pragma unroll
    for (int k = 0; k < 8; ++k) wp[k] *= ipri;
  } else {
    wp[0]=w0.x; wp[1]=w0.y; wp[2]=w0.z; wp[3]=w0.w;
    wp[4]=w1.x; wp[5]=w1.y; wp[6]=w1.z; wp[7]=w1.w;
  }
  float s = ((wp[0]+wp[1])+(wp[2]+wp[3])) + ((wp[4]+wp[5])+(wp[6]+wp[7]));
  #pragma unroll
  for (int off = 32; off > 0; off >>= 1) s += __shfl_xor(s, off, 64);

  float o[8];
  #pragma unroll
  for (int k = 0; k < 8; ++k) o[k] = -wp[k];
  if (i == 0) {
    #pragma unroll
    for (int k = 0; k < 8; ++k) o[k] = 0.f;
    if (lane == 0) o[0] = 1.f;
  } else {
    if (lane == 0) o[0] = 0.f;
    #pragma unroll
    for (int k = 0; k < 8; ++k)
      if (j0 + k == i) o[k] = s;
  }
  float* dst = Mall + (size_t)b*MS + (size_t)i*NDIM + j0;
  *(float4*)(dst)   = make_float4(o[0],o[1],o[2],o[3]);
  *(float4*)(dst+4) = make_float4(o[4],o[5],o[6],o[7]);
}

// ---------- single-wave 64x64 LU via readlane (proven) ----------
template<int KK>
struct WFact {
  static __device__ __forceinline__ void run(float (&a)[64], const int lane,
                                             float& mypiv, float& myrec) {
    const float piv = rdlane(a[KK], KK);
    const float rec = 1.0f / piv;
    if (lane == KK) { mypiv = piv; myrec = rec; }
    if (lane > KK) {
      const float l = a[KK] * rec;
      a[KK] = l;
      #pragma unroll
      for (int c = KK + 1; c < 64; ++c)
        a[c] -= l * rdlane(a[c], KK);
    }
    WFact<KK + 1>::run(a, lane, mypiv, myrec);
  }
};
template<>
struct WFact<64> {
  static __device__ __forceinline__ void run(float (&)[64], int, float&, float&) {}
};

// ---------- L21 row triangular solve, float4 LDS reads, exact ascending-p order ----------
template<int C>
struct SolveStep {
  static __device__ __forceinline__ void run(float (&a)[64], const float (*T)[68]) {
    const float* Trow = T[C];
    float acc = a[C];
    #pragma unroll
    for (int p4 = 0; p4 + 4 <= C; p4 += 4) {
      const float4 tv = *(const float4*)(Trow + p4);
      acc -= a[p4+0] * tv.x;
      acc -= a[p4+1] * tv.y;
      acc -= a[p4+2] * tv.z;
      acc -= a[p4+3] * tv.w;
    }
    #pragma unroll
    for (int p = C & ~3; p < C; ++p) acc -= a[p] * Trow[p];
    a[C] = acc * Trow[66];                    // * 1/U11[C][C]
    SolveStep<C + 1>::run(a, T);
  }
};
template<>
struct SolveStep<64> {
  static __device__ __forceinline__ void run(float (&)[64], const float (*)[68]) {}
};

// ---------- split panel: grid (129, mrem/64), 128 threads (2 waves) ----------
// every block redo's the diag LU (identical T, deterministic; fills idle CUs).
// wave0: ONE TRSM column per thread. wave1: ONE L21 row per thread (-> Lt).
// Each thread runs exactly one solve chain (R10 fused both serially).
__global__ __launch_bounds__(128) void k_panel(float* __restrict__ Mall, float* __restrict__ Lt,
                                               float* __restrict__ logdets, int k0, int mrem) {
  const int b = blockIdx.x;
  const int sub = blockIdx.y;       // 0..mrem/64-1 (or 0 when mrem==0)
  float* __restrict__ M = Mall + (size_t)b*MS;
  float* __restrict__ L = Lt + (size_t)b*LTS;
  const int t = threadIdx.x;
  __shared__ __align__(16) float T[64][68];   // T[c][r] = factored_block[r][c]; recip at [c][66]

  if (t < 64) {
    float a[64];
    const float* row = M + (size_t)(k0+t)*NDIM + k0;
    #pragma unroll
    for (int c4 = 0; c4 < 16; ++c4) {
      float4 v = *(const float4*)(row + c4*4);
      a[c4*4+0]=v.x; a[c4*4+1]=v.y; a[c4*4+2]=v.z; a[c4*4+3]=v.w;
    }
    float mypiv = 1.f, myrec = 1.f;
    WFact<0>::run(a, t, mypiv, myrec);
    #pragma unroll
    for (int c = 0; c < 64; ++c) T[c][t] = a[c];
    T[t][66] = myrec;
    if (sub == 0) {
      float v = logf(fabsf(mypiv));
      #pragma unroll
      for (int off = 32; off > 0; off >>= 1) v += __shfl_down(v, off, 64);
      if (t == 0) logdets[b] = (k0 == 0) ? v : (logdets[b] + v);
    }
  }
  __syncthreads();

  if (mrem > 0) {
    if (t < 64) {
      // wave0: TRSM column sub*64 + t
      const int col = k0 + 64 + sub*64 + t;
      float u[64];
      #pragma unroll
      for (int r = 0; r < 64; ++r) u[r] = M[(size_t)(k0+r)*NDIM + col];
      #pragma unroll
      for (int p = 0; p < 63; ++p) {
        const float lv = u[p];
        const float* Trow = T[p];
        const int kk0 = p + 1;
        const int kkA = (p + 4) & ~3;          // align-up of kk0
        #pragma unroll
        for (int kk = kk0; kk < kkA; ++kk) u[kk] -= Trow[kk] * lv;
        #pragma unroll
        for (int kk4 = kkA; kk4 < 64; kk4 += 4) {
          const float4 tv = *(const float4*)(Trow + kk4);
          u[kk4+0] -= tv.x * lv;
          u[kk4+1] -= tv.y * lv;
          u[kk4+2] -= tv.z * lv;
          u[kk4+3] -= tv.w * lv;
        }
      }
      #pragma unroll
      for (int r = 1; r < 64; ++r) M[(size_t)(k0+r)*NDIM + col] = u[r];
    } else {
      // wave1: L21 row sub*64 + (t-64) -> solve -> Lt (transposed, coalesced per c)
      const int gr = k0 + 64 + sub*64 + (t - 64);
      float a[64];
      const float* row = M + (size_t)gr*NDIM + k0;
      #pragma unroll
      for (int c4 = 0; c4 < 16; ++c4) {
        float4 v = *(const float4*)(row + c4*4);
        a[c4*4+0]=v.x; a[c4*4+1]=v.y; a[c4*4+2]=v.z; a[c4*4+3]=v.w;
      }
      SolveStep<0>::run(a, T);
      #pragma unroll
      for (int c = 0; c < 64; ++c) L[(size_t)c*NDIM + gr] = a[c];
    }
  }
}

// ---------- trailing update (R10 exact): C -= L21 * U12, 64x64 tile, 4x4/thread ----------
__global__ __launch_bounds__(256, 4) void k_gemm(float* __restrict__ Mall, const float* __restrict__ Lt,
                                                 int k0) {
  const int b = blockIdx.x;
  float* __restrict__ M = Mall + (size_t)b*MS;
  const float* __restrict__ L = Lt + (size_t)b*LTS;
  __shared__ __align__(16) float As[64][68];   // As[p][r] = L21[r][p]
  __shared__ __align__(16) float Bs[64][68];   // Bs[p][c] = U12[p][c]
  const int tid = threadIdx.x;
  const int tx = tid & 15, ty = tid >> 4;
  const int rowbase = 64 + blockIdx.y*64;
  const int colbase = 64 + blockIdx.z*64;
  #pragma unroll
  for (int i = 0; i < 4; ++i) {
    int q = tid + 256*i;           // 1024 float4
    int p = q >> 4, f = q & 15;
    *(float4*)&As[p][f*4] = *(const float4*)&L[(size_t)p*NDIM + rowbase + f*4];
    *(float4*)&Bs[p][f*4] = *(const float4*)&M[(size_t)(k0+p)*NDIM + (k0+colbase) + f*4];
  }
  float* Crow = M + (size_t)(k0+rowbase+ty*4)*NDIM + (k0+colbase+tx*4);
  float4 c0 = *(float4*)(Crow + 0*NDIM);
  float4 c1 = *(float4*)(Crow + 1*NDIM);
  float4 c2 = *(float4*)(Crow + 2*NDIM);
  float4 c3 = *(float4*)(Crow + 3*NDIM);
  __syncthreads();
  #pragma unroll
  for (int p = 0; p < 64; ++p) {
    const float4 av = *(const float4*)&As[p][ty*4];
    const float4 bv = *(const float4*)&Bs[p][tx*4];
    c0.x -= av.x*bv.x; c0.y -= av.x*bv.y; c0.z -= av.x*bv.z; c0.w -= av.x*bv.w;
    c1.x -= av.y*bv.x; c1.y -= av.y*bv.y; c1.z -= av.y*bv.z; c1.w -= av.y*bv.w;
    c2.x -= av.z*bv.x; c2.y -= av.z*bv.y; c2.z -= av.z*bv.z; c2.w -= av.z*bv.w;
    c3.x -= av.w*bv.x; c3.y -= av.w*bv.y; c3.z -= av.w*bv.z; c3.w -= av.w*bv.w;
  }
  *(float4*)(Crow + 0*NDIM) = c0;
  *(float4*)(Crow + 1*NDIM) = c1;
  *(float4*)(Crow + 2*NDIM) = c2;
  *(float4*)(Crow + 3*NDIM) = c3;
}

// ---------- final combine ----------
__global__ void k_final(const float* __restrict__ logPr, const float* __restrict__ logdets,
                        float* __restrict__ out) {
  int t = threadIdx.x;
  if (t < NB) out[t] = logPr[t] + logdets[t] - logdets[NB];
}

extern "C" void kernel_launch(void* const* d_in, const int* in_sizes, int n_in,
                              void* d_out, int out_size, void* d_ws, size_t ws_size,
                              hipStream_t stream) {
  const int*   x  = (const int*)  d_in[0];
  const float* W  = (const float*)d_in[1];
  const float* Vc = (const float*)d_in[2];
  const float* Ec = (const float*)d_in[3];
  float* out = (float*)d_out;
  float* ws  = (float*)d_ws;
  (void)in_sizes; (void)n_in; (void)out_size; (void)ws_size;  // needs ~158 MiB of ws

  float* Mat = ws + OFF_MAT;
  float* Lt  = ws + OFF_LT;
  float* Ld  = ws + OFF_LD;

  k_prep<<<1024, 256, 0, stream>>>(W, Vc, Ec, ws + OFF_WM, ws + OFF_E);
  k_Pr  <<<NB,   256, 0, stream>>>(x, Vc, ws + OFF_IPR, ws + OFF_LPR);
  dim3 gb(NMAT, 64);
  k_build<<<gb, 512, 0, stream>>>(x, ws + OFF_E, ws + OFF_WM, ws + OFF_IPR, Mat);

  for (int s = 0; s < 8; ++s) {
    const int k0 = s*64;
    const int mrem = NDIM - k0 - 64;
    dim3 gp(NMAT, (mrem > 0) ? (mrem/64) : 1);
    k_panel<<<gp, 128, 0, stream>>>(Mat, Lt, Ld, k0, mrem);
    if (mrem > 0) {
      const int nt = mrem/64;
      dim3 gg(NMAT, nt, nt);
      k_gemm<<<gg, 256, 0, stream>>>(Mat, Lt, k0);
    }
  }
  k_final<<<1, 128, 0, stream>>>(ws + OFF_LPR, Ld, out);
}